// Round 7
// baseline (498.207 us; speedup 1.0000x reference)
//
#include <hip/hip_runtime.h>

#define DD 64
#define ATT_SLOPE 0.2f
#define ACT_SLOPE 0.01f
#define GNPB 64   // nodes per block in gemm (16 per wave)

// ---------------- CSR build ----------------
// edge_index delivered as int32, flat [2,E]: src = ei[e], dst = ei[E+e].
// Self-loops (GATConv add_self_loops=True) appended as edges [E, E+N).

// Pass 1: histogram + per-edge rank (rank returned by the atomic).
__global__ void count_kernel(const int* __restrict__ ei, int E, int n_nodes,
                             int* __restrict__ counts, int* __restrict__ rank) {
    int ET = E + n_nodes;
    int e = blockIdx.x * blockDim.x + threadIdx.x;
    if (e >= ET) return;
    int d = (e < E) ? ei[E + e] : (e - E);
    rank[e] = atomicAdd(&counts[d], 1);
}

// Hierarchical scan (coalesced, whole-GPU):
__global__ void scan_blocks_kernel(const int* __restrict__ counts,
                                   int* __restrict__ scan_tmp,
                                   int* __restrict__ blk, int n) {
    __shared__ int tile[256];
    int t = threadIdx.x;
    int i = blockIdx.x * 256 + t;
    int v = (i < n) ? counts[i] : 0;
    tile[t] = v;
    __syncthreads();
    #pragma unroll
    for (int off = 1; off < 256; off <<= 1) {
        int add = (t >= off) ? tile[t - off] : 0;
        __syncthreads();
        tile[t] += add;
        __syncthreads();
    }
    if (i < n) scan_tmp[i] = tile[t] - v;
    if (t == 255) blk[blockIdx.x] = tile[255];
}

__global__ void scan_carry_kernel(int* __restrict__ blk, int nb) {
    __shared__ int tile[256];
    int t = threadIdx.x;
    int v = (t < nb) ? blk[t] : 0;
    tile[t] = v;
    __syncthreads();
    #pragma unroll
    for (int off = 1; off < 256; off <<= 1) {
        int add = (t >= off) ? tile[t - off] : 0;
        __syncthreads();
        tile[t] += add;
        __syncthreads();
    }
    if (t < nb) blk[t] = tile[t] - v;
}

__global__ void scan_final_kernel(const int* __restrict__ counts,
                                  const int* __restrict__ scan_tmp,
                                  const int* __restrict__ blk,
                                  int* __restrict__ row_ptr, int n) {
    int i = blockIdx.x * 256 + threadIdx.x;
    if (i >= n) return;
    int excl = scan_tmp[i] + blk[blockIdx.x];
    row_ptr[i + 1] = excl + counts[i];
    if (i == 0) row_ptr[0] = 0;
}

// Pass 2: atomic-free scatter using the precomputed rank.
__global__ void scatter_kernel(const int* __restrict__ ei, int E, int n_nodes,
                               const int* __restrict__ row_ptr,
                               const int* __restrict__ rank,
                               int* __restrict__ col_src) {
    int ET = E + n_nodes;
    int e = blockIdx.x * blockDim.x + threadIdx.x;
    if (e >= ET) return;
    int s, d;
    if (e < E) { s = ei[e]; d = ei[E + e]; }
    else       { s = e - E; d = s; }
    col_src[row_ptr[d] + rank[e]] = s;
}

// ---------------- per-layer kernels ----------------

// h = in @ W.T with register-resident W: lane j holds W[j][0..63] in 64 VGPRs
// (filled once per block via an LDS transpose). x rows are read through
// wave-uniform pointers (readfirstlane-forced wave id) so the compiler can
// scalarize them to s_load; 4 independent node accumulators per group.
// Fused alpha_src/alpha_dst dots via batched shuffle reduction.
__global__ __launch_bounds__(256, 4) void gemm_alpha_kernel(
        const float* __restrict__ in, const float* __restrict__ W,
        const float* __restrict__ a_src, const float* __restrict__ a_dst,
        float* __restrict__ h, float* __restrict__ as_out,
        float* __restrict__ ad_out, int n_nodes) {
    __shared__ float WT[64 * 65];   // WT[k*65+j] = W[j*64+k]
    int t = threadIdx.x;
    int lane = t & 63;
    int w = __builtin_amdgcn_readfirstlane(t >> 6);   // wave-uniform wave id

    #pragma unroll
    for (int i = 0; i < 16; ++i) {
        int idx = i * 256 + t;                 // coalesced read of W
        WT[(idx & 63) * 65 + (idx >> 6)] = W[idx];
    }
    __syncthreads();

    float wr[64];                              // W[lane][k], k = 0..63
    #pragma unroll
    for (int k = 0; k < 64; ++k) wr[k] = WT[k * 65 + lane];

    float asl = a_src[lane], adl = a_dst[lane];
    int base = blockIdx.x * GNPB + w * (GNPB / 4);   // 16 nodes per wave

    #pragma unroll 1
    for (int rq = 0; rq < 4; ++rq) {
        int n0 = base + rq * 4;
        if (n0 >= n_nodes) break;
        if (n0 + 4 <= n_nodes) {
            const float* x0 = in + (size_t)(n0 + 0) * 64;
            const float* x1 = in + (size_t)(n0 + 1) * 64;
            const float* x2 = in + (size_t)(n0 + 2) * 64;
            const float* x3 = in + (size_t)(n0 + 3) * 64;
            float a0 = 0.f, a1 = 0.f, a2 = 0.f, a3 = 0.f;
            #pragma unroll
            for (int kq = 0; kq < 16; ++kq) {
                float4 xa = *(const float4*)(x0 + kq * 4);   // uniform -> s_load
                float4 xb = *(const float4*)(x1 + kq * 4);
                float4 xc = *(const float4*)(x2 + kq * 4);
                float4 xd = *(const float4*)(x3 + kq * 4);
                a0 = fmaf(xa.x, wr[4*kq+0], a0); a0 = fmaf(xa.y, wr[4*kq+1], a0);
                a0 = fmaf(xa.z, wr[4*kq+2], a0); a0 = fmaf(xa.w, wr[4*kq+3], a0);
                a1 = fmaf(xb.x, wr[4*kq+0], a1); a1 = fmaf(xb.y, wr[4*kq+1], a1);
                a1 = fmaf(xb.z, wr[4*kq+2], a1); a1 = fmaf(xb.w, wr[4*kq+3], a1);
                a2 = fmaf(xc.x, wr[4*kq+0], a2); a2 = fmaf(xc.y, wr[4*kq+1], a2);
                a2 = fmaf(xc.z, wr[4*kq+2], a2); a2 = fmaf(xc.w, wr[4*kq+3], a2);
                a3 = fmaf(xd.x, wr[4*kq+0], a3); a3 = fmaf(xd.y, wr[4*kq+1], a3);
                a3 = fmaf(xd.z, wr[4*kq+2], a3); a3 = fmaf(xd.w, wr[4*kq+3], a3);
            }
            h[(size_t)(n0 + 0) * 64 + lane] = a0;
            h[(size_t)(n0 + 1) * 64 + lane] = a1;
            h[(size_t)(n0 + 2) * 64 + lane] = a2;
            h[(size_t)(n0 + 3) * 64 + lane] = a3;
            float s[8] = {a0 * asl, a0 * adl, a1 * asl, a1 * adl,
                          a2 * asl, a2 * adl, a3 * asl, a3 * adl};
            #pragma unroll
            for (int m = 32; m >= 1; m >>= 1) {
                #pragma unroll
                for (int i = 0; i < 8; ++i) s[i] += __shfl_xor(s[i], m, 64);
            }
            if (lane == 0) {
                as_out[n0 + 0] = s[0]; ad_out[n0 + 0] = s[1];
                as_out[n0 + 1] = s[2]; ad_out[n0 + 1] = s[3];
                as_out[n0 + 2] = s[4]; ad_out[n0 + 2] = s[5];
                as_out[n0 + 3] = s[6]; ad_out[n0 + 3] = s[7];
            }
        } else {
            for (int r = 0; r < 4; ++r) {
                int node = n0 + r;
                if (node >= n_nodes) break;
                const float* xr = in + (size_t)node * 64;
                float acc = 0.f;
                #pragma unroll
                for (int k = 0; k < 64; ++k) acc = fmaf(xr[k], wr[k], acc);
                h[(size_t)node * 64 + lane] = acc;
                float s1 = acc * asl, s2 = acc * adl;
                #pragma unroll
                for (int m = 32; m >= 1; m >>= 1) {
                    s1 += __shfl_xor(s1, m, 64);
                    s2 += __shfl_xor(s2, m, 64);
                }
                if (lane == 0) { as_out[node] = s1; ad_out[node] = s2; }
            }
        }
    }
}

// One wave per dst node; lane = (group g, float4 chunk u). 4 edges in flight
// per wave; col_src AND as_arr prefetched one iteration ahead so the h gather
// and the next logit load overlap the exp/FMA work.
template <bool FUSE_HEAD>
__global__ __launch_bounds__(256) void aggregate_kernel(
        const int* __restrict__ row_ptr, const int* __restrict__ col_src,
        const float* __restrict__ h, const float* __restrict__ as_arr,
        const float* __restrict__ ad_arr, const float* __restrict__ b,
        float* __restrict__ out, const float* __restrict__ Wout,
        const float* __restrict__ bout, int n_nodes) {
    int t = threadIdx.x;
    int w = t >> 6, lane = t & 63;
    int node = blockIdx.x * 4 + w;
    if (node >= n_nodes) return;
    int g = lane >> 4, u = lane & 15;

    int beg = __builtin_amdgcn_readfirstlane(row_ptr[node]);
    int end = __builtin_amdgcn_readfirstlane(row_ptr[node + 1]);
    float adn = ad_arr[node];

    float4 acc = {0.f, 0.f, 0.f, 0.f};
    float lsum = 0.f;
    int e = beg + g;
    int s_cur = 0; float a_cur = 0.f;
    if (e < end) { s_cur = col_src[e]; a_cur = as_arr[s_cur]; }
    while (e < end) {
        int e2 = e + 4;
        int s_nxt = 0; float a_nxt = 0.f;
        if (e2 < end) { s_nxt = col_src[e2]; a_nxt = as_arr[s_nxt]; }
        const float4 hv = *(const float4*)(h + (size_t)s_cur * 64 + u * 4);
        float lg = a_cur + adn;
        lg = (lg >= 0.f) ? lg : ATT_SLOPE * lg;
        float p = __expf(lg);
        lsum += p;
        acc.x = fmaf(p, hv.x, acc.x);
        acc.y = fmaf(p, hv.y, acc.y);
        acc.z = fmaf(p, hv.z, acc.z);
        acc.w = fmaf(p, hv.w, acc.w);
        s_cur = s_nxt; a_cur = a_nxt;
        e = e2;
    }
    #pragma unroll
    for (int m = 16; m <= 32; m <<= 1) {
        acc.x += __shfl_xor(acc.x, m, 64);
        acc.y += __shfl_xor(acc.y, m, 64);
        acc.z += __shfl_xor(acc.z, m, 64);
        acc.w += __shfl_xor(acc.w, m, 64);
        lsum  += __shfl_xor(lsum, m, 64);
    }
    float inv = 1.f / lsum;
    const float4 bv4 = *(const float4*)(b + u * 4);
    float4 o;
    o.x = acc.x * inv + bv4.x; o.x = (o.x >= 0.f) ? o.x : ACT_SLOPE * o.x;
    o.y = acc.y * inv + bv4.y; o.y = (o.y >= 0.f) ? o.y : ACT_SLOPE * o.y;
    o.z = acc.z * inv + bv4.z; o.z = (o.z >= 0.f) ? o.z : ACT_SLOPE * o.z;
    o.w = acc.w * inv + bv4.w; o.w = (o.w >= 0.f) ? o.w : ACT_SLOPE * o.w;

    if (FUSE_HEAD) {
        const float4 wv = *(const float4*)(Wout + u * 4);
        float pd = o.x * wv.x + o.y * wv.y + o.z * wv.z + o.w * wv.w;
        #pragma unroll
        for (int m = 1; m <= 8; m <<= 1) pd += __shfl_xor(pd, m, 64);
        if (lane == 0) out[node] = pd + bout[0];
    } else {
        if (g == 0) *(float4*)(out + (size_t)node * 64 + u * 4) = o;
    }
}

// ---------------- launch ----------------

extern "C" void kernel_launch(void* const* d_in, const int* in_sizes, int n_in,
                              void* d_out, int out_size, void* d_ws, size_t ws_size,
                              hipStream_t stream) {
    const float* x     = (const float*)d_in[0];
    const float* W[3]  = {(const float*)d_in[1], (const float*)d_in[5], (const float*)d_in[9]};
    const float* as[3] = {(const float*)d_in[2], (const float*)d_in[6], (const float*)d_in[10]};
    const float* ad[3] = {(const float*)d_in[3], (const float*)d_in[7], (const float*)d_in[11]};
    const float* bv[3] = {(const float*)d_in[4], (const float*)d_in[8], (const float*)d_in[12]};
    const float* Wout  = (const float*)d_in[13];
    const float* bout  = (const float*)d_in[14];
    const int*   ei    = (const int*)d_in[15];   // int64 reference -> delivered int32

    const int N  = in_sizes[0] / DD;
    const int E  = in_sizes[15] / 2;
    const int ET = E + N;

    // workspace layout (~30.8 MB; 256 B aligned)
    char* ws = (char*)d_ws;
    size_t off = 0;
    auto alloc = [&](size_t bytes) {
        void* p = ws + off;
        off = (off + bytes + 255) & ~(size_t)255;
        return p;
    };
    int*   col_src = (int*)alloc((size_t)ET * 4);
    int*   counts  = (int*)alloc((size_t)N * 4);
    int*   row_ptr = (int*)alloc((size_t)(N + 1) * 4);
    float* as_arr  = (float*)alloc((size_t)N * 4);
    float* ad_arr  = (float*)alloc((size_t)N * 4);
    float* hbuf    = (float*)alloc((size_t)N * DD * 4);
    float* obuf    = (float*)alloc((size_t)N * DD * 4);
    (void)ws_size;

    // CSR-build temporaries alias the big layer buffers (both unwritten until
    // the first gemm/aggregate, which launch after the CSR build):
    int* rank     = (int*)hbuf;          // ET ints (3.4 MB < 12.8 MB)
    int* scan_tmp = (int*)obuf;          // N ints
    int* blk      = scan_tmp + N;        // <=256 ints

    int gridET = (ET + 255) / 256;
    int gridG  = (N + GNPB - 1) / GNPB;
    int grid4  = (N + 3) / 4;
    int nb     = (N + 255) / 256;

    // CSR build (dst identical across the 3 layers -> build once per call)
    hipMemsetAsync(counts, 0, (size_t)N * 4, stream);
    count_kernel<<<gridET, 256, 0, stream>>>(ei, E, N, counts, rank);
    scan_blocks_kernel<<<nb, 256, 0, stream>>>(counts, scan_tmp, blk, N);
    scan_carry_kernel<<<1, 256, 0, stream>>>(blk, nb);
    scan_final_kernel<<<nb, 256, 0, stream>>>(counts, scan_tmp, blk, row_ptr, N);
    scatter_kernel<<<gridET, 256, 0, stream>>>(ei, E, N, row_ptr, rank, col_src);

    // 3 GAT layers; head fused into the last aggregate.
    const float* cur = x;
    for (int L = 0; L < 3; ++L) {
        gemm_alpha_kernel<<<gridG, 256, 0, stream>>>(cur, W[L], as[L], ad[L],
                                                     hbuf, as_arr, ad_arr, N);
        if (L < 2) {
            aggregate_kernel<false><<<grid4, 256, 0, stream>>>(
                row_ptr, col_src, hbuf, as_arr, ad_arr, bv[L], obuf,
                nullptr, nullptr, N);
        } else {
            aggregate_kernel<true><<<grid4, 256, 0, stream>>>(
                row_ptr, col_src, hbuf, as_arr, ad_arr, bv[L], (float*)d_out,
                Wout, bout, N);
        }
        cur = obuf;
    }
}

// Round 8
// 344.663 us; speedup vs baseline: 1.4455x; 1.4455x over previous
//
#include <hip/hip_runtime.h>

#define DD 64
#define ATT_SLOPE 0.2f
#define ACT_SLOPE 0.01f
#define GNPB 16   // nodes per block in gemm (4 per wave)

// ---------------- CSR build ----------------
// edge_index delivered as int32, flat [2,E]: src = ei[e], dst = ei[E+e].
// Self-loops (GATConv add_self_loops=True) appended as edges [E, E+N).

// Pass 1: histogram + per-edge rank (rank returned by the atomic).
__global__ void count_kernel(const int* __restrict__ ei, int E, int n_nodes,
                             int* __restrict__ counts, int* __restrict__ rank) {
    int ET = E + n_nodes;
    int e = blockIdx.x * blockDim.x + threadIdx.x;
    if (e >= ET) return;
    int d = (e < E) ? ei[E + e] : (e - E);
    rank[e] = atomicAdd(&counts[d], 1);
}

// Hierarchical scan (coalesced, whole-GPU):
__global__ void scan_blocks_kernel(const int* __restrict__ counts,
                                   int* __restrict__ scan_tmp,
                                   int* __restrict__ blk, int n) {
    __shared__ int tile[256];
    int t = threadIdx.x;
    int i = blockIdx.x * 256 + t;
    int v = (i < n) ? counts[i] : 0;
    tile[t] = v;
    __syncthreads();
    #pragma unroll
    for (int off = 1; off < 256; off <<= 1) {
        int add = (t >= off) ? tile[t - off] : 0;
        __syncthreads();
        tile[t] += add;
        __syncthreads();
    }
    if (i < n) scan_tmp[i] = tile[t] - v;
    if (t == 255) blk[blockIdx.x] = tile[255];
}

__global__ void scan_carry_kernel(int* __restrict__ blk, int nb) {
    __shared__ int tile[256];
    int t = threadIdx.x;
    int v = (t < nb) ? blk[t] : 0;
    tile[t] = v;
    __syncthreads();
    #pragma unroll
    for (int off = 1; off < 256; off <<= 1) {
        int add = (t >= off) ? tile[t - off] : 0;
        __syncthreads();
        tile[t] += add;
        __syncthreads();
    }
    if (t < nb) blk[t] = tile[t] - v;
}

__global__ void scan_final_kernel(const int* __restrict__ counts,
                                  const int* __restrict__ scan_tmp,
                                  const int* __restrict__ blk,
                                  int* __restrict__ row_ptr, int n) {
    int i = blockIdx.x * 256 + threadIdx.x;
    if (i >= n) return;
    int excl = scan_tmp[i] + blk[blockIdx.x];
    row_ptr[i + 1] = excl + counts[i];
    if (i == 0) row_ptr[0] = 0;
}

// Pass 2: atomic-free scatter using the precomputed rank.
__global__ void scatter_kernel(const int* __restrict__ ei, int E, int n_nodes,
                               const int* __restrict__ row_ptr,
                               const int* __restrict__ rank,
                               int* __restrict__ col_src) {
    int ET = E + n_nodes;
    int e = blockIdx.x * blockDim.x + threadIdx.x;
    if (e >= ET) return;
    int s, d;
    if (e < E) { s = ei[e]; d = ei[E + e]; }
    else       { s = e - E; d = s; }
    col_src[row_ptr[d] + rank[e]] = s;
}

// ---------------- per-layer kernels ----------------

// h = in @ W.T. Lane j computes output dim j; its weights are W row j --
// 256 B contiguous in global memory, L1-resident after first touch, loaded
// float4 per k-quad inside the loop (NO per-lane W array -> no spill, no LDS).
// x rows are wave-uniform s_loads (4 nodes per wave, 4 independent FMA
// chains). Fused alpha_src/alpha_dst dots via batched shuffle reduction.
__global__ void gemm_alpha_kernel(
        const float* __restrict__ in, const float* __restrict__ W,
        const float* __restrict__ a_src, const float* __restrict__ a_dst,
        float* __restrict__ h, float* __restrict__ as_out,
        float* __restrict__ ad_out, int n_nodes) {
    int t = threadIdx.x;
    int lane = t & 63;
    int w = __builtin_amdgcn_readfirstlane(t >> 6);   // wave-uniform wave id
    int n0 = blockIdx.x * GNPB + w * 4;
    if (n0 >= n_nodes) return;

    float asl = a_src[lane], adl = a_dst[lane];
    const float* wrow = W + (size_t)lane * 64;

    if (n0 + 4 <= n_nodes) {
        const float* x0 = in + (size_t)(n0 + 0) * 64;
        const float* x1 = in + (size_t)(n0 + 1) * 64;
        const float* x2 = in + (size_t)(n0 + 2) * 64;
        const float* x3 = in + (size_t)(n0 + 3) * 64;
        float a0 = 0.f, a1 = 0.f, a2 = 0.f, a3 = 0.f;
        #pragma unroll
        for (int kq = 0; kq < 16; ++kq) {
            float4 wv = *(const float4*)(wrow + kq * 4);   // L1 hit
            float4 xa = *(const float4*)(x0 + kq * 4);     // uniform -> s_load
            float4 xb = *(const float4*)(x1 + kq * 4);
            float4 xc = *(const float4*)(x2 + kq * 4);
            float4 xd = *(const float4*)(x3 + kq * 4);
            a0 = fmaf(xa.x, wv.x, a0); a0 = fmaf(xa.y, wv.y, a0);
            a0 = fmaf(xa.z, wv.z, a0); a0 = fmaf(xa.w, wv.w, a0);
            a1 = fmaf(xb.x, wv.x, a1); a1 = fmaf(xb.y, wv.y, a1);
            a1 = fmaf(xb.z, wv.z, a1); a1 = fmaf(xb.w, wv.w, a1);
            a2 = fmaf(xc.x, wv.x, a2); a2 = fmaf(xc.y, wv.y, a2);
            a2 = fmaf(xc.z, wv.z, a2); a2 = fmaf(xc.w, wv.w, a2);
            a3 = fmaf(xd.x, wv.x, a3); a3 = fmaf(xd.y, wv.y, a3);
            a3 = fmaf(xd.z, wv.z, a3); a3 = fmaf(xd.w, wv.w, a3);
        }
        h[(size_t)(n0 + 0) * 64 + lane] = a0;
        h[(size_t)(n0 + 1) * 64 + lane] = a1;
        h[(size_t)(n0 + 2) * 64 + lane] = a2;
        h[(size_t)(n0 + 3) * 64 + lane] = a3;
        float s[8] = {a0 * asl, a0 * adl, a1 * asl, a1 * adl,
                      a2 * asl, a2 * adl, a3 * asl, a3 * adl};
        #pragma unroll
        for (int m = 32; m >= 1; m >>= 1) {
            #pragma unroll
            for (int i = 0; i < 8; ++i) s[i] += __shfl_xor(s[i], m, 64);
        }
        if (lane == 0) {
            as_out[n0 + 0] = s[0]; ad_out[n0 + 0] = s[1];
            as_out[n0 + 1] = s[2]; ad_out[n0 + 1] = s[3];
            as_out[n0 + 2] = s[4]; ad_out[n0 + 2] = s[5];
            as_out[n0 + 3] = s[6]; ad_out[n0 + 3] = s[7];
        }
    } else {
        for (int r = 0; r < 4; ++r) {
            int node = n0 + r;
            if (node >= n_nodes) break;
            const float* xr = in + (size_t)node * 64;
            float acc = 0.f;
            #pragma unroll
            for (int kq = 0; kq < 16; ++kq) {
                float4 wv = *(const float4*)(wrow + kq * 4);
                float4 xa = *(const float4*)(xr + kq * 4);
                acc = fmaf(xa.x, wv.x, acc); acc = fmaf(xa.y, wv.y, acc);
                acc = fmaf(xa.z, wv.z, acc); acc = fmaf(xa.w, wv.w, acc);
            }
            h[(size_t)node * 64 + lane] = acc;
            float s1 = acc * asl, s2 = acc * adl;
            #pragma unroll
            for (int m = 32; m >= 1; m >>= 1) {
                s1 += __shfl_xor(s1, m, 64);
                s2 += __shfl_xor(s2, m, 64);
            }
            if (lane == 0) { as_out[node] = s1; ad_out[node] = s2; }
        }
    }
}

// One wave per dst node; lane = (group g, float4 chunk u). 4 edges in flight
// per wave, 2-deep pipeline: index+logit+h-row for edge i+1 are all issued
// while the exp/FMA work for edge i consumes values already in flight.
template <bool FUSE_HEAD>
__global__ __launch_bounds__(256) void aggregate_kernel(
        const int* __restrict__ row_ptr, const int* __restrict__ col_src,
        const float* __restrict__ h, const float* __restrict__ as_arr,
        const float* __restrict__ ad_arr, const float* __restrict__ b,
        float* __restrict__ out, const float* __restrict__ Wout,
        const float* __restrict__ bout, int n_nodes) {
    int t = threadIdx.x;
    int w = t >> 6, lane = t & 63;
    int node = blockIdx.x * 4 + w;
    if (node >= n_nodes) return;
    int g = lane >> 4, u = lane & 15;

    int beg = __builtin_amdgcn_readfirstlane(row_ptr[node]);
    int end = __builtin_amdgcn_readfirstlane(row_ptr[node + 1]);
    float adn = ad_arr[node];

    float4 acc = {0.f, 0.f, 0.f, 0.f};
    float lsum = 0.f;
    int e = beg + g;
    int   s0 = 0;  float a0 = 0.f;
    float4 hv0 = {0.f, 0.f, 0.f, 0.f};
    if (e < end) {
        s0 = col_src[e];
        a0 = as_arr[s0];
        hv0 = *(const float4*)(h + (size_t)s0 * 64 + u * 4);
    }
    while (e < end) {
        int e1 = e + 4;
        int s1 = 0; float a1 = 0.f;
        float4 hv1 = {0.f, 0.f, 0.f, 0.f};
        if (e1 < end) {
            s1 = col_src[e1];
            a1 = as_arr[s1];
            hv1 = *(const float4*)(h + (size_t)s1 * 64 + u * 4);
        }
        float lg = a0 + adn;
        lg = (lg >= 0.f) ? lg : ATT_SLOPE * lg;
        float p = __expf(lg);
        lsum += p;
        acc.x = fmaf(p, hv0.x, acc.x);
        acc.y = fmaf(p, hv0.y, acc.y);
        acc.z = fmaf(p, hv0.z, acc.z);
        acc.w = fmaf(p, hv0.w, acc.w);
        s0 = s1; a0 = a1; hv0 = hv1;
        e = e1;
    }
    #pragma unroll
    for (int m = 16; m <= 32; m <<= 1) {
        acc.x += __shfl_xor(acc.x, m, 64);
        acc.y += __shfl_xor(acc.y, m, 64);
        acc.z += __shfl_xor(acc.z, m, 64);
        acc.w += __shfl_xor(acc.w, m, 64);
        lsum  += __shfl_xor(lsum, m, 64);
    }
    float inv = 1.f / lsum;
    const float4 bv4 = *(const float4*)(b + u * 4);
    float4 o;
    o.x = acc.x * inv + bv4.x; o.x = (o.x >= 0.f) ? o.x : ACT_SLOPE * o.x;
    o.y = acc.y * inv + bv4.y; o.y = (o.y >= 0.f) ? o.y : ACT_SLOPE * o.y;
    o.z = acc.z * inv + bv4.z; o.z = (o.z >= 0.f) ? o.z : ACT_SLOPE * o.z;
    o.w = acc.w * inv + bv4.w; o.w = (o.w >= 0.f) ? o.w : ACT_SLOPE * o.w;

    if (FUSE_HEAD) {
        const float4 wv = *(const float4*)(Wout + u * 4);
        float pd = o.x * wv.x + o.y * wv.y + o.z * wv.z + o.w * wv.w;
        #pragma unroll
        for (int m = 1; m <= 8; m <<= 1) pd += __shfl_xor(pd, m, 64);
        if (lane == 0) out[node] = pd + bout[0];
    } else {
        if (g == 0) *(float4*)(out + (size_t)node * 64 + u * 4) = o;
    }
}

// ---------------- launch ----------------

extern "C" void kernel_launch(void* const* d_in, const int* in_sizes, int n_in,
                              void* d_out, int out_size, void* d_ws, size_t ws_size,
                              hipStream_t stream) {
    const float* x     = (const float*)d_in[0];
    const float* W[3]  = {(const float*)d_in[1], (const float*)d_in[5], (const float*)d_in[9]};
    const float* as[3] = {(const float*)d_in[2], (const float*)d_in[6], (const float*)d_in[10]};
    const float* ad[3] = {(const float*)d_in[3], (const float*)d_in[7], (const float*)d_in[11]};
    const float* bv[3] = {(const float*)d_in[4], (const float*)d_in[8], (const float*)d_in[12]};
    const float* Wout  = (const float*)d_in[13];
    const float* bout  = (const float*)d_in[14];
    const int*   ei    = (const int*)d_in[15];   // int64 reference -> delivered int32

    const int N  = in_sizes[0] / DD;
    const int E  = in_sizes[15] / 2;
    const int ET = E + N;

    // workspace layout (~30.8 MB; 256 B aligned)
    char* ws = (char*)d_ws;
    size_t off = 0;
    auto alloc = [&](size_t bytes) {
        void* p = ws + off;
        off = (off + bytes + 255) & ~(size_t)255;
        return p;
    };
    int*   col_src = (int*)alloc((size_t)ET * 4);
    int*   counts  = (int*)alloc((size_t)N * 4);
    int*   row_ptr = (int*)alloc((size_t)(N + 1) * 4);
    float* as_arr  = (float*)alloc((size_t)N * 4);
    float* ad_arr  = (float*)alloc((size_t)N * 4);
    float* hbuf    = (float*)alloc((size_t)N * DD * 4);
    float* obuf    = (float*)alloc((size_t)N * DD * 4);
    (void)ws_size;

    // CSR-build temporaries alias the big layer buffers (both unwritten until
    // the first gemm/aggregate, which launch after the CSR build):
    int* rank     = (int*)hbuf;          // ET ints (3.4 MB < 12.8 MB)
    int* scan_tmp = (int*)obuf;          // N ints
    int* blk      = scan_tmp + N;        // <=256 ints

    int gridET = (ET + 255) / 256;
    int gridG  = (N + GNPB - 1) / GNPB;
    int grid4  = (N + 3) / 4;
    int nb     = (N + 255) / 256;

    // CSR build (dst identical across the 3 layers -> build once per call)
    hipMemsetAsync(counts, 0, (size_t)N * 4, stream);
    count_kernel<<<gridET, 256, 0, stream>>>(ei, E, N, counts, rank);
    scan_blocks_kernel<<<nb, 256, 0, stream>>>(counts, scan_tmp, blk, N);
    scan_carry_kernel<<<1, 256, 0, stream>>>(blk, nb);
    scan_final_kernel<<<nb, 256, 0, stream>>>(counts, scan_tmp, blk, row_ptr, N);
    scatter_kernel<<<gridET, 256, 0, stream>>>(ei, E, N, row_ptr, rank, col_src);

    // 3 GAT layers; head fused into the last aggregate.
    const float* cur = x;
    for (int L = 0; L < 3; ++L) {
        gemm_alpha_kernel<<<gridG, 256, 0, stream>>>(cur, W[L], as[L], ad[L],
                                                     hbuf, as_arr, ad_arr, N);
        if (L < 2) {
            aggregate_kernel<false><<<grid4, 256, 0, stream>>>(
                row_ptr, col_src, hbuf, as_arr, ad_arr, bv[L], obuf,
                nullptr, nullptr, N);
        } else {
            aggregate_kernel<true><<<grid4, 256, 0, stream>>>(
                row_ptr, col_src, hbuf, as_arr, ad_arr, bv[L], (float*)d_out,
                Wout, bout, N);
        }
        cur = obuf;
    }
}

// Round 9
// 343.056 us; speedup vs baseline: 1.4523x; 1.0047x over previous
//
#include <hip/hip_runtime.h>

#define DD 64
#define ATT_SLOPE 0.2f
#define ACT_SLOPE 0.01f
#define GNPB 16   // nodes per block in gemm (4 per wave)

// ---------------- CSR build ----------------
// edge_index delivered as int32, flat [2,E]: src = ei[e], dst = ei[E+e].
// Self-loops (GATConv add_self_loops=True) are NOT materialized as edges:
// the scan adds +1 slot per node and scan_final writes the loop into the
// row's last slot analytically.

// Pass 1 (real edges only): histogram + per-edge rank from the atomic return.
__global__ void count_kernel(const int* __restrict__ ei, int E,
                             int* __restrict__ counts, int* __restrict__ rank) {
    int e = blockIdx.x * blockDim.x + threadIdx.x;
    if (e >= E) return;
    int d = ei[E + e];
    rank[e] = atomicAdd(&counts[d], 1);
}

// Scan k1: per-block local exclusive scan of (counts[i]+1) -> scan_tmp,
// block total -> blk.
__global__ void scan_blocks_kernel(const int* __restrict__ counts,
                                   int* __restrict__ scan_tmp,
                                   int* __restrict__ blk, int n) {
    __shared__ int tile[256];
    int t = threadIdx.x;
    int i = blockIdx.x * 256 + t;
    int v = (i < n) ? (counts[i] + 1) : 0;     // +1 = self-loop slot
    tile[t] = v;
    __syncthreads();
    #pragma unroll
    for (int off = 1; off < 256; off <<= 1) {
        int add = (t >= off) ? tile[t - off] : 0;
        __syncthreads();
        tile[t] += add;
        __syncthreads();
    }
    if (i < n) scan_tmp[i] = tile[t] - v;
    if (t == 255) blk[blockIdx.x] = tile[255];
}

// Scan k2 (fused carry + fixup): every block redundantly scans the <=256
// block totals in LDS, picks its carry, then writes the global exclusive
// prefix, row_ptr, and the self-loop entry (last slot of each row).
__global__ void scan_final_kernel(const int* __restrict__ counts,
                                  const int* __restrict__ scan_tmp,
                                  const int* __restrict__ blk,
                                  int* __restrict__ row_ptr,
                                  int* __restrict__ col_src, int n, int nb) {
    __shared__ int tile[256];
    int t = threadIdx.x;
    int v = (t < nb) ? blk[t] : 0;
    tile[t] = v;
    __syncthreads();
    #pragma unroll
    for (int off = 1; off < 256; off <<= 1) {
        int add = (t >= off) ? tile[t - off] : 0;
        __syncthreads();
        tile[t] += add;
        __syncthreads();
    }
    int carry = (blockIdx.x > 0) ? tile[blockIdx.x - 1] : 0;   // inclusive -> excl
    int i = blockIdx.x * 256 + t;
    if (i >= n) return;
    int excl = scan_tmp[i] + carry;
    int nxt = excl + counts[i] + 1;
    row_ptr[i + 1] = nxt;
    if (i == 0) row_ptr[0] = 0;
    col_src[nxt - 1] = i;            // self-loop occupies the row's last slot
}

// Pass 2: atomic-free scatter of the E real edges (rank slots precede the
// self-loop slot, so the two writers never collide).
__global__ void scatter_kernel(const int* __restrict__ ei, int E,
                               const int* __restrict__ row_ptr,
                               const int* __restrict__ rank,
                               int* __restrict__ col_src) {
    int e = blockIdx.x * blockDim.x + threadIdx.x;
    if (e >= E) return;
    int s = ei[e], d = ei[E + e];
    col_src[row_ptr[d] + rank[e]] = s;
}

// ---------------- per-layer kernels ----------------

// h = in @ W.T. Lane j computes output dim j; its weights are W row j --
// 256 B contiguous in global memory, L1-resident after first touch, loaded
// float4 per k-quad inside the loop (no per-lane W array -> no spill).
// x rows are wave-uniform s_loads (4 nodes per wave, 4 independent chains).
__global__ void gemm_alpha_kernel(
        const float* __restrict__ in, const float* __restrict__ W,
        const float* __restrict__ a_src, const float* __restrict__ a_dst,
        float* __restrict__ h, float* __restrict__ as_out,
        float* __restrict__ ad_out, int n_nodes) {
    int t = threadIdx.x;
    int lane = t & 63;
    int w = __builtin_amdgcn_readfirstlane(t >> 6);   // wave-uniform wave id
    int n0 = blockIdx.x * GNPB + w * 4;
    if (n0 >= n_nodes) return;

    float asl = a_src[lane], adl = a_dst[lane];
    const float* wrow = W + (size_t)lane * 64;

    if (n0 + 4 <= n_nodes) {
        const float* x0 = in + (size_t)(n0 + 0) * 64;
        const float* x1 = in + (size_t)(n0 + 1) * 64;
        const float* x2 = in + (size_t)(n0 + 2) * 64;
        const float* x3 = in + (size_t)(n0 + 3) * 64;
        float a0 = 0.f, a1 = 0.f, a2 = 0.f, a3 = 0.f;
        #pragma unroll
        for (int kq = 0; kq < 16; ++kq) {
            float4 wv = *(const float4*)(wrow + kq * 4);   // L1 hit
            float4 xa = *(const float4*)(x0 + kq * 4);     // uniform -> s_load
            float4 xb = *(const float4*)(x1 + kq * 4);
            float4 xc = *(const float4*)(x2 + kq * 4);
            float4 xd = *(const float4*)(x3 + kq * 4);
            a0 = fmaf(xa.x, wv.x, a0); a0 = fmaf(xa.y, wv.y, a0);
            a0 = fmaf(xa.z, wv.z, a0); a0 = fmaf(xa.w, wv.w, a0);
            a1 = fmaf(xb.x, wv.x, a1); a1 = fmaf(xb.y, wv.y, a1);
            a1 = fmaf(xb.z, wv.z, a1); a1 = fmaf(xb.w, wv.w, a1);
            a2 = fmaf(xc.x, wv.x, a2); a2 = fmaf(xc.y, wv.y, a2);
            a2 = fmaf(xc.z, wv.z, a2); a2 = fmaf(xc.w, wv.w, a2);
            a3 = fmaf(xd.x, wv.x, a3); a3 = fmaf(xd.y, wv.y, a3);
            a3 = fmaf(xd.z, wv.z, a3); a3 = fmaf(xd.w, wv.w, a3);
        }
        h[(size_t)(n0 + 0) * 64 + lane] = a0;
        h[(size_t)(n0 + 1) * 64 + lane] = a1;
        h[(size_t)(n0 + 2) * 64 + lane] = a2;
        h[(size_t)(n0 + 3) * 64 + lane] = a3;
        float s[8] = {a0 * asl, a0 * adl, a1 * asl, a1 * adl,
                      a2 * asl, a2 * adl, a3 * asl, a3 * adl};
        #pragma unroll
        for (int m = 32; m >= 1; m >>= 1) {
            #pragma unroll
            for (int i = 0; i < 8; ++i) s[i] += __shfl_xor(s[i], m, 64);
        }
        if (lane == 0) {
            as_out[n0 + 0] = s[0]; ad_out[n0 + 0] = s[1];
            as_out[n0 + 1] = s[2]; ad_out[n0 + 1] = s[3];
            as_out[n0 + 2] = s[4]; ad_out[n0 + 2] = s[5];
            as_out[n0 + 3] = s[6]; ad_out[n0 + 3] = s[7];
        }
    } else {
        for (int r = 0; r < 4; ++r) {
            int node = n0 + r;
            if (node >= n_nodes) break;
            const float* xr = in + (size_t)node * 64;
            float acc = 0.f;
            #pragma unroll
            for (int kq = 0; kq < 16; ++kq) {
                float4 wv = *(const float4*)(wrow + kq * 4);
                float4 xa = *(const float4*)(xr + kq * 4);
                acc = fmaf(xa.x, wv.x, acc); acc = fmaf(xa.y, wv.y, acc);
                acc = fmaf(xa.z, wv.z, acc); acc = fmaf(xa.w, wv.w, acc);
            }
            h[(size_t)node * 64 + lane] = acc;
            float s1 = acc * asl, s2 = acc * adl;
            #pragma unroll
            for (int m = 32; m >= 1; m >>= 1) {
                s1 += __shfl_xor(s1, m, 64);
                s2 += __shfl_xor(s2, m, 64);
            }
            if (lane == 0) { as_out[node] = s1; ad_out[node] = s2; }
        }
    }
}

// One wave per dst node; lane = (group g, float4 chunk u). Depth-3 software
// pipeline: 2 edges prefetched ahead per group (12 gathers in flight/wave)
// to cover the ~600-cycle L2/L3 dependent-load chain over the short (~4
// iterations/group) edge loops.
template <bool FUSE_HEAD>
__global__ __launch_bounds__(256) void aggregate_kernel(
        const int* __restrict__ row_ptr, const int* __restrict__ col_src,
        const float* __restrict__ h, const float* __restrict__ as_arr,
        const float* __restrict__ ad_arr, const float* __restrict__ b,
        float* __restrict__ out, const float* __restrict__ Wout,
        const float* __restrict__ bout, int n_nodes) {
    int t = threadIdx.x;
    int w = t >> 6, lane = t & 63;
    int node = blockIdx.x * 4 + w;
    if (node >= n_nodes) return;
    int g = lane >> 4, u = lane & 15;

    int beg = __builtin_amdgcn_readfirstlane(row_ptr[node]);
    int end = __builtin_amdgcn_readfirstlane(row_ptr[node + 1]);
    float adn = ad_arr[node];

    float4 acc = {0.f, 0.f, 0.f, 0.f};
    float lsum = 0.f;
    int e = beg + g;

    int sA = 0; float aA = 0.f; float4 hA = {0.f, 0.f, 0.f, 0.f};
    int sB = 0; float aB = 0.f; float4 hB = {0.f, 0.f, 0.f, 0.f};
    if (e < end) {
        sA = col_src[e];
        aA = as_arr[sA];
        hA = *(const float4*)(h + (size_t)sA * 64 + u * 4);
    }
    if (e + 4 < end) {
        sB = col_src[e + 4];
        aB = as_arr[sB];
        hB = *(const float4*)(h + (size_t)sB * 64 + u * 4);
    }
    while (e < end) {
        int e2 = e + 8;
        int sC = 0; float aC = 0.f; float4 hC = {0.f, 0.f, 0.f, 0.f};
        if (e2 < end) {
            sC = col_src[e2];
            aC = as_arr[sC];
            hC = *(const float4*)(h + (size_t)sC * 64 + u * 4);
        }
        float lg = aA + adn;
        lg = (lg >= 0.f) ? lg : ATT_SLOPE * lg;
        float p = __expf(lg);
        lsum += p;
        acc.x = fmaf(p, hA.x, acc.x);
        acc.y = fmaf(p, hA.y, acc.y);
        acc.z = fmaf(p, hA.z, acc.z);
        acc.w = fmaf(p, hA.w, acc.w);
        sA = sB; aA = aB; hA = hB;
        sB = sC; aB = aC; hB = hC;
        e += 4;
    }
    #pragma unroll
    for (int m = 16; m <= 32; m <<= 1) {
        acc.x += __shfl_xor(acc.x, m, 64);
        acc.y += __shfl_xor(acc.y, m, 64);
        acc.z += __shfl_xor(acc.z, m, 64);
        acc.w += __shfl_xor(acc.w, m, 64);
        lsum  += __shfl_xor(lsum, m, 64);
    }
    float inv = 1.f / lsum;
    const float4 bv4 = *(const float4*)(b + u * 4);
    float4 o;
    o.x = acc.x * inv + bv4.x; o.x = (o.x >= 0.f) ? o.x : ACT_SLOPE * o.x;
    o.y = acc.y * inv + bv4.y; o.y = (o.y >= 0.f) ? o.y : ACT_SLOPE * o.y;
    o.z = acc.z * inv + bv4.z; o.z = (o.z >= 0.f) ? o.z : ACT_SLOPE * o.z;
    o.w = acc.w * inv + bv4.w; o.w = (o.w >= 0.f) ? o.w : ACT_SLOPE * o.w;

    if (FUSE_HEAD) {
        const float4 wv = *(const float4*)(Wout + u * 4);
        float pd = o.x * wv.x + o.y * wv.y + o.z * wv.z + o.w * wv.w;
        #pragma unroll
        for (int m = 1; m <= 8; m <<= 1) pd += __shfl_xor(pd, m, 64);
        if (lane == 0) out[node] = pd + bout[0];
    } else {
        if (g == 0) *(float4*)(out + (size_t)node * 64 + u * 4) = o;
    }
}

// ---------------- launch ----------------

extern "C" void kernel_launch(void* const* d_in, const int* in_sizes, int n_in,
                              void* d_out, int out_size, void* d_ws, size_t ws_size,
                              hipStream_t stream) {
    const float* x     = (const float*)d_in[0];
    const float* W[3]  = {(const float*)d_in[1], (const float*)d_in[5], (const float*)d_in[9]};
    const float* as[3] = {(const float*)d_in[2], (const float*)d_in[6], (const float*)d_in[10]};
    const float* ad[3] = {(const float*)d_in[3], (const float*)d_in[7], (const float*)d_in[11]};
    const float* bv[3] = {(const float*)d_in[4], (const float*)d_in[8], (const float*)d_in[12]};
    const float* Wout  = (const float*)d_in[13];
    const float* bout  = (const float*)d_in[14];
    const int*   ei    = (const int*)d_in[15];   // int64 reference -> delivered int32

    const int N  = in_sizes[0] / DD;
    const int E  = in_sizes[15] / 2;
    const int ET = E + N;

    // workspace layout (~30.8 MB; 256 B aligned)
    char* ws = (char*)d_ws;
    size_t off = 0;
    auto alloc = [&](size_t bytes) {
        void* p = ws + off;
        off = (off + bytes + 255) & ~(size_t)255;
        return p;
    };
    int*   col_src = (int*)alloc((size_t)ET * 4);
    int*   counts  = (int*)alloc((size_t)N * 4);
    int*   row_ptr = (int*)alloc((size_t)(N + 1) * 4);
    float* as_arr  = (float*)alloc((size_t)N * 4);
    float* ad_arr  = (float*)alloc((size_t)N * 4);
    float* hbuf    = (float*)alloc((size_t)N * DD * 4);
    float* obuf    = (float*)alloc((size_t)N * DD * 4);
    (void)ws_size;

    // CSR-build temporaries alias the big layer buffers (both unwritten until
    // the first gemm/aggregate, which launch after the CSR build):
    int* rank     = (int*)hbuf;          // E ints (3.2 MB < 12.8 MB)
    int* scan_tmp = (int*)obuf;          // N ints
    int* blk      = scan_tmp + N;        // <=256 ints

    int gridE  = (E + 255) / 256;
    int gridG  = (N + GNPB - 1) / GNPB;
    int grid4  = (N + 3) / 4;
    int nb     = (N + 255) / 256;

    // CSR build (dst identical across the 3 layers -> build once per call)
    hipMemsetAsync(counts, 0, (size_t)N * 4, stream);
    count_kernel<<<gridE, 256, 0, stream>>>(ei, E, counts, rank);
    scan_blocks_kernel<<<nb, 256, 0, stream>>>(counts, scan_tmp, blk, N);
    scan_final_kernel<<<nb, 256, 0, stream>>>(counts, scan_tmp, blk, row_ptr,
                                              col_src, N, nb);
    scatter_kernel<<<gridE, 256, 0, stream>>>(ei, E, row_ptr, rank, col_src);

    // 3 GAT layers; head fused into the last aggregate.
    const float* cur = x;
    for (int L = 0; L < 3; ++L) {
        gemm_alpha_kernel<<<gridG, 256, 0, stream>>>(cur, W[L], as[L], ad[L],
                                                     hbuf, as_arr, ad_arr, N);
        if (L < 2) {
            aggregate_kernel<false><<<grid4, 256, 0, stream>>>(
                row_ptr, col_src, hbuf, as_arr, ad_arr, bv[L], obuf,
                nullptr, nullptr, N);
        } else {
            aggregate_kernel<true><<<grid4, 256, 0, stream>>>(
                row_ptr, col_src, hbuf, as_arr, ad_arr, bv[L], (float*)d_out,
                Wout, bout, N);
        }
        cur = obuf;
    }
}